// Round 7
// baseline (1227.853 us; speedup 1.0000x reference)
//
#include <hip/hip_runtime.h>
#include <math.h>

#define BB 8
#define NN 2048
#define DD 256
#define KNN 8
#define NPTS (BB*NN)        // 16384
#define NEDGE (NPTS*KNN)    // 131072
#define BN_EPS 1e-5f
#define NSH 64              // shadow copies for stats accumulation (atomic decontention)

// ---- workspace layout (float offsets) ----
#define OFF_X      0
#define OFF_FEAT   (OFF_X + NPTS*DD)
#define OFF_SQ     (OFF_FEAT + NPTS*3*DD)
#define OFF_IDX    (OFF_SQ + NPTS)
#define OFF_U      (OFF_IDX + NEDGE)
#define OFF_V      (OFF_U + NPTS*DD)
#define OFF_WU     (OFF_V + NPTS*DD)
#define OFF_W2P    (OFF_WU + DD*DD)
#define OFF_BIASP  (OFF_W2P + DD*DD)
#define OFF_STATS  (OFF_BIASP + DD)           // NSH rows x 1024
#define OFF_MAXK   (OFF_STATS + NSH*1024)
#define OFF_MINK   (OFF_MAXK + NPTS*DD)
#define OFF_PMAX   (OFF_MINK + NPTS*DD)
#define OFF_PMIN   (OFF_PMAX + BB*32*DD)

__device__ __forceinline__ float block_sum256(float v, float* red, int tid) {
  #pragma unroll
  for (int off = 32; off; off >>= 1) v += __shfl_down(v, off, 64);
  __syncthreads();
  if ((tid & 63) == 0) red[tid >> 6] = v;
  __syncthreads();
  return red[0] + red[1] + red[2] + red[3];
}

// branchless top-8 merge of two sorted-ascending 8-lists (values + indices):
// a = 8 smallest of union(a,b), sorted ascending. ~84 VALU, no divergence.
__device__ __forceinline__ void bmerge8(float* a, int* aj, const float* b, const int* bj) {
  float L[8]; int J[8];
  #pragma unroll
  for (int i = 0; i < 8; i++) {
    bool t = a[i] <= b[7-i];
    L[i] = t ? a[i] : b[7-i];
    J[i] = t ? aj[i] : bj[7-i];
  }
  // L is bitonic; sort ascending: stages dist 4,2,1
  #pragma unroll
  for (int st = 4; st >= 1; st >>= 1) {
    #pragma unroll
    for (int i = 0; i < 8; i++) {
      if ((i & st) == 0) {
        int p = i + st;
        bool sw = L[i] > L[p];
        float tv = L[i]; int tj = J[i];
        L[i] = sw ? L[p] : L[i];  J[i] = sw ? J[p] : J[i];
        L[p] = sw ? tv   : L[p];  J[p] = sw ? tj   : J[p];
      }
    }
  }
  #pragma unroll
  for (int i = 0; i < 8; i++) { a[i] = L[i]; aj[i] = J[i]; }
}

// ---------------- per-point features -> feat[16384,768] (each 256-chunk l2-normalized)
__global__ __launch_bounds__(256) void featurize(
    const int* __restrict__ cls, const float* __restrict__ colors, const float* __restrict__ positions,
    const float* __restrict__ ctab,
    const float* __restrict__ pW1, const float* __restrict__ pb1, const float* __restrict__ pW2, const float* __restrict__ pb2,
    const float* __restrict__ cW1, const float* __restrict__ cb1, const float* __restrict__ cW2, const float* __restrict__ cb2,
    float* __restrict__ feat)
{
  __shared__ float colh[32], posh[32];
  __shared__ float red[4];
  int p = blockIdx.x;
  int tid = threadIdx.x;
  float c0 = colors[p*3+0], c1 = colors[p*3+1], c2 = colors[p*3+2];
  float q0 = positions[p*3+0], q1 = positions[p*3+1], q2 = positions[p*3+2];
  if (tid < 32) {
    colh[tid] = fmaxf(c0*cW1[tid] + c1*cW1[32+tid] + c2*cW1[64+tid] + cb1[tid], 0.f);
    posh[tid] = fmaxf(q0*pW1[tid] + q1*pW1[32+tid] + q2*pW1[64+tid] + pb1[tid], 0.f);
  }
  __syncthreads();
  int c = tid;
  float ce = ctab[cls[p]*DD + c];
  float col = cb2[c], pos = pb2[c];
  #pragma unroll
  for (int k = 0; k < 32; k++) {
    col += colh[k]*cW2[k*DD + c];
    pos += posh[k]*pW2[k*DD + c];
  }
  col = fmaxf(col, 0.f); pos = fmaxf(pos, 0.f);
  float sce  = block_sum256(ce*ce,  red, tid);
  float scol = block_sum256(col*col, red, tid);
  float spos = block_sum256(pos*pos, red, tid);
  float* fp = feat + (size_t)p*768;
  fp[c]       = ce  / fmaxf(sqrtf(sce),  1e-12f);
  fp[256 + c] = col / fmaxf(sqrtf(scol), 1e-12f);
  fp[512 + c] = pos / fmaxf(sqrtf(spos), 1e-12f);
}

// ---------------- generic 64x64-tile GEMM: C[M,256] = act(A[M,KD] @ W[KD,256] (+bias))
template<int KD, bool RELU, bool HASBIAS>
__global__ __launch_bounds__(256) void gemm64(
    const float* __restrict__ A, const float* __restrict__ W, const float* __restrict__ bias,
    float* __restrict__ C)
{
  __shared__ float aT[32][68];
  __shared__ float bS[32][68];
  int tid = threadIdx.x;
  int tx = tid & 15, ty = tid >> 4;
  int rowbase = blockIdx.x * 64;
  int colbase = blockIdx.y * 64;
  int sr = tid >> 2, sk = (tid & 3) * 8;
  float acc[4][4] = {};
  for (int kc = 0; kc < KD; kc += 32) {
    const float* ap = A + (size_t)(rowbase + sr)*KD + kc + sk;
    float4 a0 = *(const float4*)ap;
    float4 a1 = *(const float4*)(ap + 4);
    const float* wp = W + (size_t)(kc + ty)*DD + colbase + tx*4;
    float4 b0  = *(const float4*)wp;
    float4 b1v = *(const float4*)(wp + (size_t)16*DD);
    __syncthreads();
    aT[sk+0][sr]=a0.x; aT[sk+1][sr]=a0.y; aT[sk+2][sr]=a0.z; aT[sk+3][sr]=a0.w;
    aT[sk+4][sr]=a1.x; aT[sk+5][sr]=a1.y; aT[sk+6][sr]=a1.z; aT[sk+7][sr]=a1.w;
    *(float4*)&bS[ty][tx*4]      = b0;
    *(float4*)&bS[ty + 16][tx*4] = b1v;
    __syncthreads();
    #pragma unroll
    for (int k = 0; k < 32; k++) {
      float4 av = *(const float4*)&aT[k][ty*4];
      float4 bv = *(const float4*)&bS[k][tx*4];
      float a_[4] = {av.x, av.y, av.z, av.w};
      float b_[4] = {bv.x, bv.y, bv.z, bv.w};
      #pragma unroll
      for (int rr = 0; rr < 4; rr++)
        #pragma unroll
        for (int cc = 0; cc < 4; cc++)
          acc[rr][cc] += a_[rr]*b_[cc];
    }
  }
  #pragma unroll
  for (int rr = 0; rr < 4; rr++) {
    int row = rowbase + ty*4 + rr;
    float o[4];
    #pragma unroll
    for (int cc = 0; cc < 4; cc++) {
      float v = acc[rr][cc];
      if (HASBIAS) v += bias[colbase + tx*4 + cc];
      if (RELU) v = fmaxf(v, 0.f);
      o[cc] = v;
    }
    *(float4*)&C[(size_t)row*DD + colbase + tx*4] = make_float4(o[0],o[1],o[2],o[3]);
  }
}

// ---------------- fused u/v GEMM: u = x@(W1top - W1bot), v = x@W1bot (stage x once)
__global__ __launch_bounds__(256) void gemmuv(
    const float* __restrict__ A, const float* __restrict__ gW1,
    float* __restrict__ U, float* __restrict__ V)
{
  __shared__ float aT[32][68];
  __shared__ float bU[32][68];
  __shared__ float bV[32][68];
  int tid = threadIdx.x;
  int tx = tid & 15, ty = tid >> 4;
  int rowbase = blockIdx.x * 64;
  int colbase = blockIdx.y * 64;
  int sr = tid >> 2, sk = (tid & 3) * 8;
  float accU[4][4] = {}, accV[4][4] = {};
  for (int kc = 0; kc < DD; kc += 32) {
    const float* ap = A + (size_t)(rowbase + sr)*DD + kc + sk;
    float4 a0 = *(const float4*)ap;
    float4 a1 = *(const float4*)(ap + 4);
    const float* wt = gW1 + (size_t)(kc + ty)*DD + colbase + tx*4;
    const float* wb = wt + (size_t)DD*DD;
    float4 t0 = *(const float4*)wt;
    float4 t1 = *(const float4*)(wt + (size_t)16*DD);
    float4 o0 = *(const float4*)wb;
    float4 o1 = *(const float4*)(wb + (size_t)16*DD);
    __syncthreads();
    aT[sk+0][sr]=a0.x; aT[sk+1][sr]=a0.y; aT[sk+2][sr]=a0.z; aT[sk+3][sr]=a0.w;
    aT[sk+4][sr]=a1.x; aT[sk+5][sr]=a1.y; aT[sk+6][sr]=a1.z; aT[sk+7][sr]=a1.w;
    *(float4*)&bU[ty][tx*4]      = make_float4(t0.x-o0.x, t0.y-o0.y, t0.z-o0.z, t0.w-o0.w);
    *(float4*)&bU[ty + 16][tx*4] = make_float4(t1.x-o1.x, t1.y-o1.y, t1.z-o1.z, t1.w-o1.w);
    *(float4*)&bV[ty][tx*4]      = o0;
    *(float4*)&bV[ty + 16][tx*4] = o1;
    __syncthreads();
    #pragma unroll
    for (int k = 0; k < 32; k++) {
      float4 av = *(const float4*)&aT[k][ty*4];
      float4 bu = *(const float4*)&bU[k][tx*4];
      float4 bv = *(const float4*)&bV[k][tx*4];
      float a_[4] = {av.x, av.y, av.z, av.w};
      float u_[4] = {bu.x, bu.y, bu.z, bu.w};
      float v_[4] = {bv.x, bv.y, bv.z, bv.w};
      #pragma unroll
      for (int rr = 0; rr < 4; rr++)
        #pragma unroll
        for (int cc = 0; cc < 4; cc++) {
          accU[rr][cc] += a_[rr]*u_[cc];
          accV[rr][cc] += a_[rr]*v_[cc];
        }
    }
  }
  #pragma unroll
  for (int rr = 0; rr < 4; rr++) {
    int row = rowbase + ty*4 + rr;
    *(float4*)&U[(size_t)row*DD + colbase + tx*4] =
        make_float4(accU[rr][0], accU[rr][1], accU[rr][2], accU[rr][3]);
    *(float4*)&V[(size_t)row*DD + colbase + tx*4] =
        make_float4(accV[rr][0], accV[rr][1], accV[rr][2], accV[rr][3]);
  }
}

// ---------------- sum-of-squares per point (one wave per point)
__global__ __launch_bounds__(256) void sqk(const float* __restrict__ x, float* __restrict__ sq) {
  int tid = threadIdx.x;
  int p = blockIdx.x*4 + (tid >> 6);
  int lane = tid & 63;
  float4 v = *(const float4*)&x[(size_t)p*DD + lane*4];
  float s = v.x*v.x + v.y*v.y + v.z*v.z + v.w*v.w;
  #pragma unroll
  for (int off = 32; off; off >>= 1) s += __shfl_down(s, off, 64);
  if (lane == 0) sq[p] = s;
}

// ---------------- kNN partial: per (batch, 128-row i-tile, j-eighth of 256), keep top-8.
// 128x128 j-tiles, 4x16 micro-tile (0.3125 LDS floats/FMA vs 0.5 at 4x4).
// B columns strided (q*32 + col_g*4) so all b128 reads are conflict-free.
// Selection in registers; 3-step lane butterfly with branchless bitonic merges.
__global__ __launch_bounds__(256) void knnk(const float* __restrict__ x, const float* __restrict__ sq,
                                            float* __restrict__ pdg, int* __restrict__ pjg)
{
  __shared__ float aT[32][132];
  __shared__ float bT[32][132];
  __shared__ float sqI[128], sqJ[128];
  int tid = threadIdx.x;
  int q8 = blockIdx.x & 7;
  int it = (blockIdx.x >> 3) & 15;
  int bb = blockIdx.x >> 7;
  int ibase = it * 128;
  const float* xb  = x  + (size_t)bb*NN*DD;
  const float* sqb = sq + (size_t)bb*NN;
  int row_g = tid >> 3;        // 0..31 (4 rows each)
  int col_g = tid & 7;         // 0..7  (16 strided cols each)
  int sr = tid >> 1;           // staging row 0..127
  int sk = (tid & 1) * 16;     // staging k-offset 0/16
  if (tid < 128) sqI[tid] = sqb[ibase + tid];
  __syncthreads();
  float sqi[4];
  #pragma unroll
  for (int rr = 0; rr < 4; rr++) sqi[rr] = sqI[row_g*4 + rr];
  float ld[4][8]; int lj[4][8];
  #pragma unroll
  for (int rr = 0; rr < 4; rr++)
    #pragma unroll
    for (int s = 0; s < 8; s++) { ld[rr][s] = 3.4e38f; lj[rr][s] = 0; }
  #pragma unroll 1
  for (int jt = 0; jt < 2; jt++) {
    int jbase = q8*256 + jt*128;
    float acc[4][16] = {};
    #pragma unroll 1
    for (int kc = 0; kc < DD; kc += 32) {
      const float* ap = xb + (size_t)(ibase + sr)*DD + kc + sk;
      float4 a0 = *(const float4*)ap;
      float4 a1 = *(const float4*)(ap + 4);
      float4 a2 = *(const float4*)(ap + 8);
      float4 a3 = *(const float4*)(ap + 12);
      const float* bp = xb + (size_t)(jbase + sr)*DD + kc + sk;
      float4 b0 = *(const float4*)bp;
      float4 b1 = *(const float4*)(bp + 4);
      float4 b2 = *(const float4*)(bp + 8);
      float4 b3 = *(const float4*)(bp + 12);
      float sjv = 0.f;
      if (kc == 0 && tid < 128) sjv = sqb[jbase + tid];
      __syncthreads();
      aT[sk+ 0][sr]=a0.x; aT[sk+ 1][sr]=a0.y; aT[sk+ 2][sr]=a0.z; aT[sk+ 3][sr]=a0.w;
      aT[sk+ 4][sr]=a1.x; aT[sk+ 5][sr]=a1.y; aT[sk+ 6][sr]=a1.z; aT[sk+ 7][sr]=a1.w;
      aT[sk+ 8][sr]=a2.x; aT[sk+ 9][sr]=a2.y; aT[sk+10][sr]=a2.z; aT[sk+11][sr]=a2.w;
      aT[sk+12][sr]=a3.x; aT[sk+13][sr]=a3.y; aT[sk+14][sr]=a3.z; aT[sk+15][sr]=a3.w;
      bT[sk+ 0][sr]=b0.x; bT[sk+ 1][sr]=b0.y; bT[sk+ 2][sr]=b0.z; bT[sk+ 3][sr]=b0.w;
      bT[sk+ 4][sr]=b1.x; bT[sk+ 5][sr]=b1.y; bT[sk+ 6][sr]=b1.z; bT[sk+ 7][sr]=b1.w;
      bT[sk+ 8][sr]=b2.x; bT[sk+ 9][sr]=b2.y; bT[sk+10][sr]=b2.z; bT[sk+11][sr]=b2.w;
      bT[sk+12][sr]=b3.x; bT[sk+13][sr]=b3.y; bT[sk+14][sr]=b3.z; bT[sk+15][sr]=b3.w;
      if (kc == 0 && tid < 128) sqJ[tid] = sjv;
      __syncthreads();
      #pragma unroll
      for (int k = 0; k < 32; k++) {
        float4 av = *(const float4*)&aT[k][row_g*4];
        float a_[4] = {av.x, av.y, av.z, av.w};
        #pragma unroll
        for (int q = 0; q < 4; q++) {
          float4 bv = *(const float4*)&bT[k][q*32 + col_g*4];
          float b_[4] = {bv.x, bv.y, bv.z, bv.w};
          #pragma unroll
          for (int rr = 0; rr < 4; rr++)
            #pragma unroll
            for (int cc = 0; cc < 4; cc++)
              acc[rr][q*4+cc] += a_[rr]*b_[cc];
        }
      }
    }
    // selection: d = sqI[r] + sqJ[c] - 2*acc (same formula as reference)
    float sj[16];
    #pragma unroll
    for (int q = 0; q < 4; q++)
      #pragma unroll
      for (int cc = 0; cc < 4; cc++) sj[q*4+cc] = sqJ[q*32 + col_g*4 + cc];
    #pragma unroll
    for (int rr = 0; rr < 4; rr++) {
      #pragma unroll
      for (int ci = 0; ci < 16; ci++) {
        float dv = sqi[rr] + sj[ci] - 2.f*acc[rr][ci];
        if (dv < ld[rr][7]) {
          ld[rr][7] = dv; lj[rr][7] = jbase + (ci >> 2)*32 + col_g*4 + (ci & 3);
          #pragma unroll
          for (int t = 7; t >= 1; t--) {
            if (ld[rr][t] < ld[rr][t-1]) {
              float td = ld[rr][t]; ld[rr][t] = ld[rr][t-1]; ld[rr][t-1] = td;
              int   tj = lj[rr][t]; lj[rr][t] = lj[rr][t-1]; lj[rr][t-1] = tj;
            }
          }
        }
      }
    }
    __syncthreads();   // protect sqJ/aT/bT for next tile
  }
  // butterfly merge over the 8 lanes (col_g) sharing each row group (masks 1,2,4 stay in-wave)
  #pragma unroll
  for (int m = 1; m <= 4; m <<= 1) {
    #pragma unroll
    for (int rr = 0; rr < 4; rr++) {
      float od[8]; int oj[8];
      #pragma unroll
      for (int s = 0; s < 8; s++) {
        od[s] = __shfl_xor(ld[rr][s], m, 64);
        oj[s] = __shfl_xor(lj[rr][s], m, 64);
      }
      bmerge8(ld[rr], lj[rr], od, oj);
    }
  }
  if (col_g == 0) {
    #pragma unroll
    for (int rr = 0; rr < 4; rr++) {
      int row = row_g*4 + rr;
      size_t gbase = ((size_t)(bb*NN + ibase + row))*64 + (size_t)q8*8;
      *(float4*)&pdg[gbase]     = make_float4(ld[rr][0], ld[rr][1], ld[rr][2], ld[rr][3]);
      *(float4*)&pdg[gbase + 4] = make_float4(ld[rr][4], ld[rr][5], ld[rr][6], ld[rr][7]);
      #pragma unroll
      for (int s = 0; s < 8; s++) pjg[gbase + s] = bb*NN + lj[rr][s];
    }
  }
}

// ---------------- merge 8 eighth-lists per point -> final 8 neighbor indices
__global__ __launch_bounds__(256) void knnmerge(const float* __restrict__ pdg, const int* __restrict__ pjg,
                                                int* __restrict__ idxg)
{
  int p = blockIdx.x*256 + threadIdx.x;
  float md[8]; int mj[8];
  #pragma unroll
  for (int s = 0; s < 8; s++) { md[s] = 3.4e38f; mj[s] = 0; }
  size_t base = (size_t)p*64;
  #pragma unroll 1
  for (int s = 0; s < 64; s++) {
    float dv = pdg[base + s];
    if (dv < md[7]) {
      md[7] = dv; mj[7] = pjg[base + s];
      #pragma unroll
      for (int t = 7; t >= 1; t--) {
        if (md[t] < md[t-1]) {
          float td = md[t]; md[t] = md[t-1]; md[t-1] = td;
          int   tj = mj[t]; mj[t] = mj[t-1]; mj[t-1] = tj;
        }
      }
    }
  }
  #pragma unroll
  for (int s = 0; s < 8; s++) idxg[(size_t)p*8 + s] = mj[s];
}

// ---------------- BN1 stats: h1 = relu(u_i + v_j + b1), shadow-accumulator atomics
__global__ __launch_bounds__(256) void bn1stats(const float* __restrict__ u, const float* __restrict__ v,
    const int* __restrict__ idxg, const float* __restrict__ b1, float* __restrict__ stats)
{
  __shared__ int jL[256];
  int c = threadIdx.x;
  int n0 = blockIdx.x * 32;
  jL[c] = idxg[(size_t)n0*8 + c];
  __syncthreads();
  float b1c = b1[c];
  float s = 0.f, s2 = 0.f;
  #pragma unroll 1
  for (int n = 0; n < 32; n++) {
    float uc = u[(size_t)(n0 + n)*DD + c];
    #pragma unroll
    for (int e = 0; e < 8; e++) {
      int j = jL[n*8 + e];
      float h = fmaxf(uc + v[(size_t)j*DD + c] + b1c, 0.f);
      s += h; s2 += h*h;
    }
  }
  int row = blockIdx.x & (NSH - 1);
  atomicAdd(&stats[row*1024 + c], s);
  atomicAdd(&stats[row*1024 + 256 + c], s2);
}

// ---------------- fold BN1 into layer-2 weights: W2' = diag(s1) W2 ; bias' = b2 + t1.W2
__global__ __launch_bounds__(256) void prep2(const float* __restrict__ stats, const float* __restrict__ g1,
    const float* __restrict__ be1, const float* __restrict__ gW2, const float* __restrict__ gb2,
    float* __restrict__ W2p, float* __restrict__ biasp)
{
  __shared__ float s1L[256], t1L[256];
  int tid = threadIdx.x;
  const float inv = 1.f / (float)NEDGE;
  float sm = 0.f, sq2 = 0.f;
  #pragma unroll 1
  for (int r = 0; r < NSH; r++) {
    sm  += stats[r*1024 + tid];
    sq2 += stats[r*1024 + 256 + tid];
  }
  float m = sm * inv;
  float var = sq2*inv - m*m;
  float s1 = g1[tid] / sqrtf(var + BN_EPS);
  s1L[tid] = s1; t1L[tid] = be1[tid] - m*s1;
  __syncthreads();
  float bacc = gb2[tid];
  for (int k = 0; k < DD; k++) {
    float w = gW2[k*DD + tid];
    W2p[k*DD + tid] = s1L[k]*w;
    bacc += t1L[k]*w;
  }
  biasp[tid] = bacc;
}

// ---------------- edge GEMM: h2 = relu( relu(u_i+v_j+b1) @ W2' + bias' )
__global__ __launch_bounds__(256) void edgek(
    const float* __restrict__ u, const float* __restrict__ v, const int* __restrict__ idxg,
    const float* __restrict__ b1, const float* __restrict__ W2p, const float* __restrict__ biasp,
    float* __restrict__ maxK, float* __restrict__ minK, float* __restrict__ stats)
{
  __shared__ float aT[32][68];
  __shared__ float bS[32][260];
  __shared__ int   jL[64];
  __shared__ float redS[4][256];
  __shared__ float redQ[4][256];
  int tid = threadIdx.x;
  int tx = tid & 15, ty = tid >> 4;
  int rowbase = blockIdx.x * 64;
  if (tid < 64) jL[tid] = idxg[rowbase + tid];
  __syncthreads();
  int sr = tid >> 2, sk = (tid & 3) * 8;
  int iu = (rowbase + sr) >> 3;
  int bk = tid >> 6;            // 0..3
  int bc = (tid & 63) * 4;
  float acc[4][16] = {};
  for (int kc = 0; kc < DD; kc += 32) {
    int jv = jL[sr];
    const float* uq = u + (size_t)iu*DD + kc + sk;
    float4 u0 = *(const float4*)uq;
    float4 u1 = *(const float4*)(uq + 4);
    const float* vq = v + (size_t)jv*DD + kc + sk;
    float4 v0 = *(const float4*)vq;
    float4 v1 = *(const float4*)(vq + 4);
    float4 c0 = *(const float4*)&b1[kc + sk];
    float4 c1 = *(const float4*)&b1[kc + sk + 4];
    float4 wreg[8];
    #pragma unroll
    for (int kk = 0; kk < 8; kk++)
      wreg[kk] = *(const float4*)&W2p[(size_t)(kc + bk + kk*4)*DD + bc];
    __syncthreads();
    aT[sk+0][sr] = fmaxf(u0.x+v0.x+c0.x, 0.f);
    aT[sk+1][sr] = fmaxf(u0.y+v0.y+c0.y, 0.f);
    aT[sk+2][sr] = fmaxf(u0.z+v0.z+c0.z, 0.f);
    aT[sk+3][sr] = fmaxf(u0.w+v0.w+c0.w, 0.f);
    aT[sk+4][sr] = fmaxf(u1.x+v1.x+c1.x, 0.f);
    aT[sk+5][sr] = fmaxf(u1.y+v1.y+c1.y, 0.f);
    aT[sk+6][sr] = fmaxf(u1.z+v1.z+c1.z, 0.f);
    aT[sk+7][sr] = fmaxf(u1.w+v1.w+c1.w, 0.f);
    #pragma unroll
    for (int kk = 0; kk < 8; kk++)
      *(float4*)&bS[bk + kk*4][bc] = wreg[kk];
    __syncthreads();
    #pragma unroll
    for (int k = 0; k < 32; k++) {
      float4 av = *(const float4*)&aT[k][ty*4];
      float a_[4] = {av.x, av.y, av.z, av.w};
      #pragma unroll
      for (int q = 0; q < 4; q++) {
        float4 bv = *(const float4*)&bS[k][q*64 + tx*4];
        float b_[4] = {bv.x, bv.y, bv.z, bv.w};
        #pragma unroll
        for (int rr = 0; rr < 4; rr++)
          #pragma unroll
          for (int cc = 0; cc < 4; cc++)
            acc[rr][q*4+cc] += a_[rr]*b_[cc];
      }
    }
  }
  float mx[16], mn[16], sS[16], sQ[16];
  #pragma unroll
  for (int q4 = 0; q4 < 4; q4++) {
    #pragma unroll
    for (int cc = 0; cc < 4; cc++) {
      int col = q4*64 + tx*4 + cc;
      float bp = biasp[col];
      int q = q4*4 + cc;
      float h0 = fmaxf(acc[0][q] + bp, 0.f);
      float h1 = fmaxf(acc[1][q] + bp, 0.f);
      float h2 = fmaxf(acc[2][q] + bp, 0.f);
      float h3 = fmaxf(acc[3][q] + bp, 0.f);
      mx[q] = fmaxf(fmaxf(h0,h1), fmaxf(h2,h3));
      mn[q] = fminf(fminf(h0,h1), fminf(h2,h3));
      sS[q] = h0+h1+h2+h3;
      sQ[q] = h0*h0+h1*h1+h2*h2+h3*h3;
    }
  }
  #pragma unroll
  for (int q = 0; q < 16; q++) {
    mx[q] = fmaxf(mx[q], __shfl_xor(mx[q], 16, 64));
    mn[q] = fminf(mn[q], __shfl_xor(mn[q], 16, 64));
  }
  if ((ty & 1) == 0) {
    int node = (rowbase >> 3) + (ty >> 1);
    #pragma unroll
    for (int q4 = 0; q4 < 4; q4++) {
      *(float4*)&maxK[(size_t)node*DD + q4*64 + tx*4] =
          make_float4(mx[q4*4+0], mx[q4*4+1], mx[q4*4+2], mx[q4*4+3]);
      *(float4*)&minK[(size_t)node*DD + q4*64 + tx*4] =
          make_float4(mn[q4*4+0], mn[q4*4+1], mn[q4*4+2], mn[q4*4+3]);
    }
  }
  #pragma unroll
  for (int q = 0; q < 16; q++) {
    sS[q] += __shfl_xor(sS[q], 16, 64);
    sS[q] += __shfl_xor(sS[q], 32, 64);
    sQ[q] += __shfl_xor(sQ[q], 16, 64);
    sQ[q] += __shfl_xor(sQ[q], 32, 64);
  }
  int w = tid >> 6;
  if ((tid & 63) < 16) {
    #pragma unroll
    for (int q4 = 0; q4 < 4; q4++)
      #pragma unroll
      for (int cc = 0; cc < 4; cc++) {
        redS[w][q4*64 + tx*4 + cc] = sS[q4*4+cc];
        redQ[w][q4*64 + tx*4 + cc] = sQ[q4*4+cc];
      }
  }
  __syncthreads();
  float ts = redS[0][tid]+redS[1][tid]+redS[2][tid]+redS[3][tid];
  float tq = redQ[0][tid]+redQ[1][tid]+redQ[2][tid]+redQ[3][tid];
  int row = blockIdx.x & (NSH - 1);
  atomicAdd(&stats[row*1024 + 512 + tid], ts);
  atomicAdd(&stats[row*1024 + 768 + tid], tq);
}

// ---------------- partial max/min over n (64 rows per block)
__global__ __launch_bounds__(256) void poolpart(const float* __restrict__ maxK, const float* __restrict__ minK,
    float* __restrict__ pmax, float* __restrict__ pmin)
{
  int b = blockIdx.x, ns = blockIdx.y, c = threadIdx.x;
  float mx = -3.4e38f, mn = 3.4e38f;
  size_t base = ((size_t)b*NN + ns*64)*DD + c;
  for (int n = 0; n < 64; n++) {
    mx = fmaxf(mx, maxK[base + (size_t)n*DD]);
    mn = fminf(mn, minK[base + (size_t)n*DD]);
  }
  pmax[((size_t)b*32 + ns)*DD + c] = mx;
  pmin[((size_t)b*32 + ns)*DD + c] = mn;
}

// ---------------- final: BN2 on pooled max/min, two 256x256 linears, l2norm
__global__ __launch_bounds__(256) void finalk(const float* __restrict__ pmax, const float* __restrict__ pmin,
    const float* __restrict__ stats, const float* __restrict__ g2, const float* __restrict__ be2,
    const float* __restrict__ W1, const float* __restrict__ b1,
    const float* __restrict__ W2, const float* __restrict__ b2,
    float* __restrict__ out)
{
  __shared__ float pl[8][256];
  __shared__ float hl[8][256];
  __shared__ float nrm[8];
  int c = threadIdx.x;
  const float inv = 1.f / (float)NEDGE;
  float sm = 0.f, sq2 = 0.f;
  #pragma unroll 1
  for (int r = 0; r < NSH; r++) {
    sm  += stats[r*1024 + 512 + c];
    sq2 += stats[r*1024 + 768 + c];
  }
  float m = sm * inv;
  float var = sq2*inv - m*m;
  float s2 = g2[c] / sqrtf(var + BN_EPS);
  float t2 = be2[c] - m*s2;
  #pragma unroll
  for (int b = 0; b < 8; b++) {
    float mx = -3.4e38f, mn = 3.4e38f;
    for (int ns = 0; ns < 32; ns++) {
      mx = fmaxf(mx, pmax[((size_t)b*32+ns)*DD + c]);
      mn = fminf(mn, pmin[((size_t)b*32+ns)*DD + c]);
    }
    pl[b][c] = (s2 >= 0.f) ? s2*mx + t2 : s2*mn + t2;
  }
  __syncthreads();
  float h[8];
  #pragma unroll
  for (int b = 0; b < 8; b++) h[b] = b1[c];
  for (int k = 0; k < 256; k++) {
    float w = W1[k*256 + c];
    #pragma unroll
    for (int b = 0; b < 8; b++) h[b] += pl[b][k]*w;
  }
  __syncthreads();
  #pragma unroll
  for (int b = 0; b < 8; b++) hl[b][c] = fmaxf(h[b], 0.f);
  __syncthreads();
  float o[8];
  #pragma unroll
  for (int b = 0; b < 8; b++) o[b] = b2[c];
  for (int k = 0; k < 256; k++) {
    float w = W2[k*256 + c];
    #pragma unroll
    for (int b = 0; b < 8; b++) o[b] += hl[b][k]*w;
  }
  __syncthreads();
  #pragma unroll
  for (int b = 0; b < 8; b++) pl[b][c] = fmaxf(o[b], 0.f);
  __syncthreads();
  if (c < 8) {
    float s = 0.f;
    for (int k = 0; k < 256; k++) { float vv = pl[c][k]; s += vv*vv; }
    nrm[c] = fmaxf(sqrtf(s), 1e-12f);
  }
  __syncthreads();
  #pragma unroll
  for (int b = 0; b < 8; b++) out[b*256 + c] = pl[b][c] / nrm[b];
}

extern "C" void kernel_launch(void* const* d_in, const int* in_sizes, int n_in,
                              void* d_out, int out_size, void* d_ws, size_t ws_size,
                              hipStream_t stream) {
  (void)in_sizes; (void)n_in; (void)out_size; (void)ws_size;
  const int*   cls       = (const int*)  d_in[0];
  const float* colors    = (const float*)d_in[1];
  const float* positions = (const float*)d_in[2];
  const float* ctab      = (const float*)d_in[3];
  const float* pW1 = (const float*)d_in[4];
  const float* pb1 = (const float*)d_in[5];
  const float* pW2 = (const float*)d_in[6];
  const float* pb2 = (const float*)d_in[7];
  const float* cW1 = (const float*)d_in[8];
  const float* cb1 = (const float*)d_in[9];
  const float* cW2 = (const float*)d_in[10];
  const float* cb2 = (const float*)d_in[11];
  const float* mW  = (const float*)d_in[12];
  const float* mb  = (const float*)d_in[13];
  const float* gW1 = (const float*)d_in[14];
  const float* gb1 = (const float*)d_in[15];
  const float* gg1 = (const float*)d_in[16];
  const float* gbe1= (const float*)d_in[17];
  const float* gW2 = (const float*)d_in[18];
  const float* gb2 = (const float*)d_in[19];
  const float* gg2 = (const float*)d_in[20];
  const float* gbe2= (const float*)d_in[21];
  const float* lW1 = (const float*)d_in[22];
  const float* lb1 = (const float*)d_in[23];
  const float* lW2 = (const float*)d_in[24];
  const float* lb2 = (const float*)d_in[25];
  float* out = (float*)d_out;

  float* wsf   = (float*)d_ws;
  float* x     = wsf + OFF_X;
  float* feat  = wsf + OFF_FEAT;
  float* sq    = wsf + OFF_SQ;
  int*   idxg  = (int*)(wsf + OFF_IDX);
  float* u     = wsf + OFF_U;
  float* v     = wsf + OFF_V;
  float* W2p   = wsf + OFF_W2P;
  float* biasp = wsf + OFF_BIASP;
  float* stats = wsf + OFF_STATS;
  float* maxK  = wsf + OFF_MAXK;
  float* minK  = wsf + OFF_MINK;
  float* pmax  = wsf + OFF_PMAX;
  float* pmin  = wsf + OFF_PMIN;
  // partial kNN buffers overlay feat (dead after the merge GEMM): 64 entries/point
  float* pdg   = feat;
  int*   pjg   = (int*)(feat + (size_t)NPTS*64);

  hipMemsetAsync(stats, 0, NSH*1024*sizeof(float), stream);

  featurize<<<NPTS, 256, 0, stream>>>(cls, colors, positions, ctab,
                                      pW1, pb1, pW2, pb2, cW1, cb1, cW2, cb2, feat);
  gemm64<768, true, true><<<dim3(NPTS/64, 4), 256, 0, stream>>>(feat, mW, mb, x);
  sqk<<<NPTS/4, 256, 0, stream>>>(x, sq);
  knnk<<<BB*16*8, 256, 0, stream>>>(x, sq, pdg, pjg);
  knnmerge<<<NPTS/256, 256, 0, stream>>>(pdg, pjg, idxg);
  gemmuv<<<dim3(NPTS/64, 4), 256, 0, stream>>>(x, gW1, u, v);
  bn1stats<<<NPTS/32, 256, 0, stream>>>(u, v, idxg, gb1, stats);
  prep2<<<1, 256, 0, stream>>>(stats, gg1, gbe1, gW2, gb2, W2p, biasp);
  edgek<<<NEDGE/64, 256, 0, stream>>>(u, v, idxg, gb1, W2p, biasp, maxK, minK, stats);
  poolpart<<<dim3(BB, 32), 256, 0, stream>>>(maxK, minK, pmax, pmin);
  finalk<<<1, 256, 0, stream>>>(pmax, pmin, stats, gg2, gbe2, lW1, lb1, lW2, lb2, out);
}

// Round 8
// 932.965 us; speedup vs baseline: 1.3161x; 1.3161x over previous
//
#include <hip/hip_runtime.h>
#include <math.h>

#define BB 8
#define NN 2048
#define DD 256
#define KNN 8
#define NPTS (BB*NN)        // 16384
#define NEDGE (NPTS*KNN)    // 131072
#define BN_EPS 1e-5f
#define NSH 64              // shadow copies for stats accumulation (atomic decontention)

// ---- workspace layout (float offsets) ----
#define OFF_X      0
#define OFF_FEAT   (OFF_X + NPTS*DD)
#define OFF_SQ     (OFF_FEAT + NPTS*3*DD)
#define OFF_IDX    (OFF_SQ + NPTS)
#define OFF_U      (OFF_IDX + NEDGE)
#define OFF_V      (OFF_U + NPTS*DD)
#define OFF_WU     (OFF_V + NPTS*DD)
#define OFF_W2P    (OFF_WU + DD*DD)
#define OFF_BIASP  (OFF_W2P + DD*DD)
#define OFF_STATS  (OFF_BIASP + DD)           // NSH rows x 1024
#define OFF_MAXK   (OFF_STATS + NSH*1024)
#define OFF_MINK   (OFF_MAXK + NPTS*DD)
#define OFF_PMAX   (OFF_MINK + NPTS*DD)
#define OFF_PMIN   (OFF_PMAX + BB*32*DD)

// async global->LDS, 16B per lane; lbase must be wave-uniform, dest = lbase + lane*16B
__device__ __forceinline__ void gload_lds16(const float* g, float* lbase) {
#if defined(__has_builtin) && __has_builtin(__builtin_amdgcn_global_load_lds)
  __builtin_amdgcn_global_load_lds(
      (const __attribute__((address_space(1))) void*)(g),
      (__attribute__((address_space(3))) void*)(lbase),
      16, 0, 0);
#else
  int lane = threadIdx.x & 63;
  *(float4*)(lbase + lane*4) = *(const float4*)g;
#endif
}

__device__ __forceinline__ float block_sum256(float v, float* red, int tid) {
  #pragma unroll
  for (int off = 32; off; off >>= 1) v += __shfl_down(v, off, 64);
  __syncthreads();
  if ((tid & 63) == 0) red[tid >> 6] = v;
  __syncthreads();
  return red[0] + red[1] + red[2] + red[3];
}

// ---------------- per-point features -> feat[16384,768] (each 256-chunk l2-normalized)
__global__ __launch_bounds__(256) void featurize(
    const int* __restrict__ cls, const float* __restrict__ colors, const float* __restrict__ positions,
    const float* __restrict__ ctab,
    const float* __restrict__ pW1, const float* __restrict__ pb1, const float* __restrict__ pW2, const float* __restrict__ pb2,
    const float* __restrict__ cW1, const float* __restrict__ cb1, const float* __restrict__ cW2, const float* __restrict__ cb2,
    float* __restrict__ feat)
{
  __shared__ float colh[32], posh[32];
  __shared__ float red[4];
  int p = blockIdx.x;
  int tid = threadIdx.x;
  float c0 = colors[p*3+0], c1 = colors[p*3+1], c2 = colors[p*3+2];
  float q0 = positions[p*3+0], q1 = positions[p*3+1], q2 = positions[p*3+2];
  if (tid < 32) {
    colh[tid] = fmaxf(c0*cW1[tid] + c1*cW1[32+tid] + c2*cW1[64+tid] + cb1[tid], 0.f);
    posh[tid] = fmaxf(q0*pW1[tid] + q1*pW1[32+tid] + q2*pW1[64+tid] + pb1[tid], 0.f);
  }
  __syncthreads();
  int c = tid;
  float ce = ctab[cls[p]*DD + c];
  float col = cb2[c], pos = pb2[c];
  #pragma unroll
  for (int k = 0; k < 32; k++) {
    col += colh[k]*cW2[k*DD + c];
    pos += posh[k]*pW2[k*DD + c];
  }
  col = fmaxf(col, 0.f); pos = fmaxf(pos, 0.f);
  float sce  = block_sum256(ce*ce,  red, tid);
  float scol = block_sum256(col*col, red, tid);
  float spos = block_sum256(pos*pos, red, tid);
  float* fp = feat + (size_t)p*768;
  fp[c]       = ce  / fmaxf(sqrtf(sce),  1e-12f);
  fp[256 + c] = col / fmaxf(sqrtf(scol), 1e-12f);
  fp[512 + c] = pos / fmaxf(sqrtf(spos), 1e-12f);
}

// ---------------- generic 64x64-tile GEMM: C[M,256] = act(A[M,KD] @ W[KD,256] (+bias))
// B staged via global_load_lds DMA into unpadded stride-64 LDS (conflict-free reads).
template<int KD, bool RELU, bool HASBIAS>
__global__ __launch_bounds__(256) void gemm64(
    const float* __restrict__ A, const float* __restrict__ W, const float* __restrict__ bias,
    float* __restrict__ C)
{
  __shared__ float aT[32][68];
  __shared__ float bS[32*64];
  int tid = threadIdx.x;
  int tx = tid & 15, ty = tid >> 4;
  int rowbase = blockIdx.x * 64;
  int colbase = blockIdx.y * 64;
  int sr = tid >> 2, sk = (tid & 3) * 8;
  int lane = tid & 63, wv = tid >> 6;
  float acc[4][4] = {};
  for (int kc = 0; kc < KD; kc += 32) {
    const float* ap = A + (size_t)(rowbase + sr)*KD + kc + sk;
    float4 a0 = *(const float4*)ap;
    float4 a1 = *(const float4*)(ap + 4);
    __syncthreads();
    #pragma unroll
    for (int r = 0; r < 2; r++) {
      int R0 = r*16 + wv*4;
      gload_lds16(W + (size_t)(kc + R0 + (lane >> 4))*DD + colbase + (lane & 15)*4,
                  &bS[R0*64]);
    }
    aT[sk+0][sr]=a0.x; aT[sk+1][sr]=a0.y; aT[sk+2][sr]=a0.z; aT[sk+3][sr]=a0.w;
    aT[sk+4][sr]=a1.x; aT[sk+5][sr]=a1.y; aT[sk+6][sr]=a1.z; aT[sk+7][sr]=a1.w;
    __syncthreads();
    #pragma unroll
    for (int k = 0; k < 32; k++) {
      float4 av = *(const float4*)&aT[k][ty*4];
      float4 bv = *(const float4*)&bS[k*64 + tx*4];
      float a_[4] = {av.x, av.y, av.z, av.w};
      float b_[4] = {bv.x, bv.y, bv.z, bv.w};
      #pragma unroll
      for (int rr = 0; rr < 4; rr++)
        #pragma unroll
        for (int cc = 0; cc < 4; cc++)
          acc[rr][cc] += a_[rr]*b_[cc];
    }
  }
  #pragma unroll
  for (int rr = 0; rr < 4; rr++) {
    int row = rowbase + ty*4 + rr;
    float o[4];
    #pragma unroll
    for (int cc = 0; cc < 4; cc++) {
      float v = acc[rr][cc];
      if (HASBIAS) v += bias[colbase + tx*4 + cc];
      if (RELU) v = fmaxf(v, 0.f);
      o[cc] = v;
    }
    *(float4*)&C[(size_t)row*DD + colbase + tx*4] = make_float4(o[0],o[1],o[2],o[3]);
  }
}

// ---------------- Wu = W1_top - W1_bot
__global__ __launch_bounds__(256) void prep_wu(const float* __restrict__ gW1, float* __restrict__ Wu) {
  int i = blockIdx.x*256 + threadIdx.x;
  Wu[i] = gW1[i] - gW1[i + DD*DD];
}

// ---------------- fused u/v GEMM: u = x@Wu, v = x@W1bot (stage x once, weights via DMA)
__global__ __launch_bounds__(256) void gemmuv(
    const float* __restrict__ A, const float* __restrict__ Wu, const float* __restrict__ Wb,
    float* __restrict__ U, float* __restrict__ V)
{
  __shared__ float aT[32][68];
  __shared__ float bU[32*64];
  __shared__ float bV[32*64];
  int tid = threadIdx.x;
  int tx = tid & 15, ty = tid >> 4;
  int rowbase = blockIdx.x * 64;
  int colbase = blockIdx.y * 64;
  int sr = tid >> 2, sk = (tid & 3) * 8;
  int lane = tid & 63, wv = tid >> 6;
  float accU[4][4] = {}, accV[4][4] = {};
  for (int kc = 0; kc < DD; kc += 32) {
    const float* ap = A + (size_t)(rowbase + sr)*DD + kc + sk;
    float4 a0 = *(const float4*)ap;
    float4 a1 = *(const float4*)(ap + 4);
    __syncthreads();
    #pragma unroll
    for (int r = 0; r < 2; r++) {
      int R0 = r*16 + wv*4;
      size_t goff = (size_t)(kc + R0 + (lane >> 4))*DD + colbase + (lane & 15)*4;
      gload_lds16(Wu + goff, &bU[R0*64]);
      gload_lds16(Wb + goff, &bV[R0*64]);
    }
    aT[sk+0][sr]=a0.x; aT[sk+1][sr]=a0.y; aT[sk+2][sr]=a0.z; aT[sk+3][sr]=a0.w;
    aT[sk+4][sr]=a1.x; aT[sk+5][sr]=a1.y; aT[sk+6][sr]=a1.z; aT[sk+7][sr]=a1.w;
    __syncthreads();
    #pragma unroll
    for (int k = 0; k < 32; k++) {
      float4 av = *(const float4*)&aT[k][ty*4];
      float4 bu = *(const float4*)&bU[k*64 + tx*4];
      float4 bv = *(const float4*)&bV[k*64 + tx*4];
      float a_[4] = {av.x, av.y, av.z, av.w};
      float u_[4] = {bu.x, bu.y, bu.z, bu.w};
      float v_[4] = {bv.x, bv.y, bv.z, bv.w};
      #pragma unroll
      for (int rr = 0; rr < 4; rr++)
        #pragma unroll
        for (int cc = 0; cc < 4; cc++) {
          accU[rr][cc] += a_[rr]*u_[cc];
          accV[rr][cc] += a_[rr]*v_[cc];
        }
    }
  }
  #pragma unroll
  for (int rr = 0; rr < 4; rr++) {
    int row = rowbase + ty*4 + rr;
    *(float4*)&U[(size_t)row*DD + colbase + tx*4] =
        make_float4(accU[rr][0], accU[rr][1], accU[rr][2], accU[rr][3]);
    *(float4*)&V[(size_t)row*DD + colbase + tx*4] =
        make_float4(accV[rr][0], accV[rr][1], accV[rr][2], accV[rr][3]);
  }
}

// ---------------- sum-of-squares per point (one wave per point)
__global__ __launch_bounds__(256) void sqk(const float* __restrict__ x, float* __restrict__ sq) {
  int tid = threadIdx.x;
  int p = blockIdx.x*4 + (tid >> 6);
  int lane = tid & 63;
  float4 v = *(const float4*)&x[(size_t)p*DD + lane*4];
  float s = v.x*v.x + v.y*v.y + v.z*v.z + v.w*v.w;
  #pragma unroll
  for (int off = 32; off; off >>= 1) s += __shfl_down(s, off, 64);
  if (lane == 0) sq[p] = s;
}

// ---------------- kNN partial: per (batch, 64-row i-tile, j-quarter), keep 8 smallest d
// R4-proven structure (dt matrix + 256-thread selection) + XOR-16 staging swizzle.
__global__ __launch_bounds__(256) void knnk(const float* __restrict__ x, const float* __restrict__ sq,
                                            float* __restrict__ pdg, int* __restrict__ pjg)
{
  __shared__ float aT[32][68];
  __shared__ float bT[32][68];
  __shared__ float dt[64][65];
  __shared__ float sqI[64], sqJ[64];
  int tid = threadIdx.x;
  int q  = blockIdx.x & 3;
  int it = (blockIdx.x >> 2) & 31;
  int bb = blockIdx.x >> 7;
  int ibase = it * 64;
  const float* xb  = x  + (size_t)bb*NN*DD;
  const float* sqb = sq + (size_t)bb*NN;
  int tx = tid & 15, ty = tid >> 4;
  int sr = tid >> 2, sk = (tid & 3) * 8;
  int srw = sr ^ ((tid & 1) << 4);   // staging-write swizzle (breaks 4-way bank conflict)
  int selrow = tid & 63, selseg = tid >> 6;
  float bd[8]; int bj[8];
  #pragma unroll
  for (int s = 0; s < 8; s++) { bd[s] = 3.4e38f; bj[s] = 0; }
  if (tid < 64) sqI[tid] = sqb[ibase + tid];
  for (int jt = 0; jt < 8; jt++) {
    int jbase = q*512 + jt*64;
    float acc[4][4] = {};
    for (int kc = 0; kc < DD; kc += 32) {
      const float* ap = xb + (size_t)(ibase + sr)*DD + kc + sk;
      float4 a0 = *(const float4*)ap;
      float4 a1 = *(const float4*)(ap + 4);
      const float* bp = xb + (size_t)(jbase + sr)*DD + kc + sk;
      float4 b0  = *(const float4*)bp;
      float4 b1v = *(const float4*)(bp + 4);
      float sjv = 0.f;
      if (kc == 0 && tid < 64) sjv = sqb[jbase + tid];
      __syncthreads();
      aT[sk+0][srw]=a0.x; aT[sk+1][srw]=a0.y; aT[sk+2][srw]=a0.z; aT[sk+3][srw]=a0.w;
      aT[sk+4][srw]=a1.x; aT[sk+5][srw]=a1.y; aT[sk+6][srw]=a1.z; aT[sk+7][srw]=a1.w;
      bT[sk+0][srw]=b0.x; bT[sk+1][srw]=b0.y; bT[sk+2][srw]=b0.z; bT[sk+3][srw]=b0.w;
      bT[sk+4][srw]=b1v.x; bT[sk+5][srw]=b1v.y; bT[sk+6][srw]=b1v.z; bT[sk+7][srw]=b1v.w;
      if (kc == 0 && tid < 64) sqJ[tid] = sjv;
      __syncthreads();
      #pragma unroll
      for (int k = 0; k < 32; k++) {
        int rsw = ((k >> 3) & 1) << 4;
        float4 av = *(const float4*)&aT[k][(ty*4) ^ rsw];
        float4 bv = *(const float4*)&bT[k][(tx*4) ^ rsw];
        float a_[4] = {av.x, av.y, av.z, av.w};
        float b_[4] = {bv.x, bv.y, bv.z, bv.w};
        #pragma unroll
        for (int rr = 0; rr < 4; rr++)
          #pragma unroll
          for (int cc = 0; cc < 4; cc++)
            acc[rr][cc] += a_[rr]*b_[cc];
      }
    }
    #pragma unroll
    for (int rr = 0; rr < 4; rr++)
      #pragma unroll
      for (int cc = 0; cc < 4; cc++)
        dt[ty*4+rr][tx*4+cc] = sqI[ty*4+rr] + sqJ[tx*4+cc] - 2.f*acc[rr][cc];
    __syncthreads();
    int cb = selseg*16;
    #pragma unroll
    for (int s = 0; s < 16; s++) {
      float dv = dt[selrow][cb + s];
      if (dv < bd[7]) {
        bd[7] = dv; bj[7] = jbase + cb + s;
        #pragma unroll
        for (int t = 7; t >= 1; t--) {
          if (bd[t] < bd[t-1]) {
            float td = bd[t]; bd[t] = bd[t-1]; bd[t-1] = td;
            int   tj = bj[t]; bj[t] = bj[t-1]; bj[t-1] = tj;
          }
        }
      }
    }
    __syncthreads();
  }
  // stage per-thread lists in LDS (overlay aT/bT — GEMM done)
  float* pdl = &aT[0][0];
  int*   pjl = (int*)&bT[0][0];
  #pragma unroll
  for (int s = 0; s < 8; s++) {
    pdl[tid*8 + s] = bd[s];
    pjl[tid*8 + s] = bj[s];
  }
  __syncthreads();
  if (tid < 64) {
    float md[8]; int mj[8];
    #pragma unroll
    for (int s = 0; s < 8; s++) { md[s] = 3.4e38f; mj[s] = 0; }
    #pragma unroll 1
    for (int g = 0; g < 4; g++) {
      int base = (g*64 + tid)*8;
      #pragma unroll
      for (int s = 0; s < 8; s++) {
        float dv = pdl[base + s];
        if (dv < md[7]) {
          md[7] = dv; mj[7] = pjl[base + s];
          #pragma unroll
          for (int t = 7; t >= 1; t--) {
            if (md[t] < md[t-1]) {
              float td = md[t]; md[t] = md[t-1]; md[t-1] = td;
              int   tj = mj[t]; mj[t] = mj[t-1]; mj[t-1] = tj;
            }
          }
        }
      }
    }
    size_t gbase = ((size_t)(bb*NN + ibase + tid))*32 + (size_t)q*8;
    #pragma unroll
    for (int s = 0; s < 8; s++) {
      pdg[gbase + s] = md[s];
      pjg[gbase + s] = bb*NN + mj[s];
    }
  }
}

// ---------------- merge 4 quarter-lists per point -> final 8 neighbor indices
__global__ __launch_bounds__(256) void knnmerge(const float* __restrict__ pdg, const int* __restrict__ pjg,
                                                int* __restrict__ idxg)
{
  int p = blockIdx.x*256 + threadIdx.x;
  float md[8]; int mj[8];
  #pragma unroll
  for (int s = 0; s < 8; s++) { md[s] = 3.4e38f; mj[s] = 0; }
  size_t base = (size_t)p*32;
  #pragma unroll 1
  for (int s = 0; s < 32; s++) {
    float dv = pdg[base + s];
    if (dv < md[7]) {
      md[7] = dv; mj[7] = pjg[base + s];
      #pragma unroll
      for (int t = 7; t >= 1; t--) {
        if (md[t] < md[t-1]) {
          float td = md[t]; md[t] = md[t-1]; md[t-1] = td;
          int   tj = mj[t]; mj[t] = mj[t-1]; mj[t-1] = tj;
        }
      }
    }
  }
  #pragma unroll
  for (int s = 0; s < 8; s++) idxg[(size_t)p*8 + s] = mj[s];
}

// ---------------- BN1 stats: h1 = relu(u_i + v_j + b1), shadow-accumulator atomics
__global__ __launch_bounds__(256) void bn1stats(const float* __restrict__ u, const float* __restrict__ v,
    const int* __restrict__ idxg, const float* __restrict__ b1, float* __restrict__ stats)
{
  __shared__ int jL[256];
  int c = threadIdx.x;
  int n0 = blockIdx.x * 32;
  jL[c] = idxg[(size_t)n0*8 + c];
  __syncthreads();
  float b1c = b1[c];
  float s = 0.f, s2 = 0.f;
  #pragma unroll 1
  for (int n = 0; n < 32; n++) {
    float uc = u[(size_t)(n0 + n)*DD + c];
    #pragma unroll
    for (int e = 0; e < 8; e++) {
      int j = jL[n*8 + e];
      float h = fmaxf(uc + v[(size_t)j*DD + c] + b1c, 0.f);
      s += h; s2 += h*h;
    }
  }
  int row = blockIdx.x & (NSH - 1);
  atomicAdd(&stats[row*1024 + c], s);
  atomicAdd(&stats[row*1024 + 256 + c], s2);
}

// ---------------- fold BN1 into layer-2 weights: W2' = diag(s1) W2 ; bias' = b2 + t1.W2
__global__ __launch_bounds__(256) void prep2(const float* __restrict__ stats, const float* __restrict__ g1,
    const float* __restrict__ be1, const float* __restrict__ gW2, const float* __restrict__ gb2,
    float* __restrict__ W2p, float* __restrict__ biasp)
{
  __shared__ float s1L[256], t1L[256];
  int tid = threadIdx.x;
  const float inv = 1.f / (float)NEDGE;
  float sm = 0.f, sq2 = 0.f;
  #pragma unroll 1
  for (int r = 0; r < NSH; r++) {
    sm  += stats[r*1024 + tid];
    sq2 += stats[r*1024 + 256 + tid];
  }
  float m = sm * inv;
  float var = sq2*inv - m*m;
  float s1 = g1[tid] / sqrtf(var + BN_EPS);
  s1L[tid] = s1; t1L[tid] = be1[tid] - m*s1;
  __syncthreads();
  float bacc = gb2[tid];
  for (int k = 0; k < DD; k++) {
    float w = gW2[k*DD + tid];
    W2p[k*DD + tid] = s1L[k]*w;
    bacc += t1L[k]*w;
  }
  biasp[tid] = bacc;
}

// ---------------- edge GEMM: h2 = relu( relu(u_i+v_j+b1) @ W2' + bias' )
// W2p staged via global_load_lds DMA into unpadded stride-256 LDS (conflict-free reads).
__global__ __launch_bounds__(256) void edgek(
    const float* __restrict__ u, const float* __restrict__ v, const int* __restrict__ idxg,
    const float* __restrict__ b1, const float* __restrict__ W2p, const float* __restrict__ biasp,
    float* __restrict__ maxK, float* __restrict__ minK, float* __restrict__ stats)
{
  __shared__ float aT[32][68];
  __shared__ float bS[32*256];
  __shared__ int   jL[64];
  __shared__ float redS[4][256];
  __shared__ float redQ[4][256];
  int tid = threadIdx.x;
  int tx = tid & 15, ty = tid >> 4;
  int rowbase = blockIdx.x * 64;
  if (tid < 64) jL[tid] = idxg[rowbase + tid];
  __syncthreads();
  int sr = tid >> 2, sk = (tid & 3) * 8;
  int iu = (rowbase + sr) >> 3;
  int lane = tid & 63, wv = tid >> 6;
  float acc[4][16] = {};
  for (int kc = 0; kc < DD; kc += 32) {
    int jv = jL[sr];
    const float* uq = u + (size_t)iu*DD + kc + sk;
    float4 u0 = *(const float4*)uq;
    float4 u1 = *(const float4*)(uq + 4);
    const float* vq = v + (size_t)jv*DD + kc + sk;
    float4 v0 = *(const float4*)vq;
    float4 v1 = *(const float4*)(vq + 4);
    float4 c0 = *(const float4*)&b1[kc + sk];
    float4 c1 = *(const float4*)&b1[kc + sk + 4];
    __syncthreads();
    #pragma unroll
    for (int rI = 0; rI < 8; rI++) {
      int R = rI*4 + wv;
      gload_lds16(W2p + (size_t)(kc + R)*DD + lane*4, &bS[R*256]);
    }
    aT[sk+0][sr] = fmaxf(u0.x+v0.x+c0.x, 0.f);
    aT[sk+1][sr] = fmaxf(u0.y+v0.y+c0.y, 0.f);
    aT[sk+2][sr] = fmaxf(u0.z+v0.z+c0.z, 0.f);
    aT[sk+3][sr] = fmaxf(u0.w+v0.w+c0.w, 0.f);
    aT[sk+4][sr] = fmaxf(u1.x+v1.x+c1.x, 0.f);
    aT[sk+5][sr] = fmaxf(u1.y+v1.y+c1.y, 0.f);
    aT[sk+6][sr] = fmaxf(u1.z+v1.z+c1.z, 0.f);
    aT[sk+7][sr] = fmaxf(u1.w+v1.w+c1.w, 0.f);
    __syncthreads();
    #pragma unroll
    for (int k = 0; k < 32; k++) {
      float4 av = *(const float4*)&aT[k][ty*4];
      float a_[4] = {av.x, av.y, av.z, av.w};
      #pragma unroll
      for (int q = 0; q < 4; q++) {
        float4 bv = *(const float4*)&bS[k*256 + q*64 + tx*4];
        float b_[4] = {bv.x, bv.y, bv.z, bv.w};
        #pragma unroll
        for (int rr = 0; rr < 4; rr++)
          #pragma unroll
          for (int cc = 0; cc < 4; cc++)
            acc[rr][q*4+cc] += a_[rr]*b_[cc];
      }
    }
  }
  float mx[16], mn[16], sS[16], sQ[16];
  #pragma unroll
  for (int q4 = 0; q4 < 4; q4++) {
    #pragma unroll
    for (int cc = 0; cc < 4; cc++) {
      int col = q4*64 + tx*4 + cc;
      float bp = biasp[col];
      int q = q4*4 + cc;
      float h0 = fmaxf(acc[0][q] + bp, 0.f);
      float h1 = fmaxf(acc[1][q] + bp, 0.f);
      float h2 = fmaxf(acc[2][q] + bp, 0.f);
      float h3 = fmaxf(acc[3][q] + bp, 0.f);
      mx[q] = fmaxf(fmaxf(h0,h1), fmaxf(h2,h3));
      mn[q] = fminf(fminf(h0,h1), fminf(h2,h3));
      sS[q] = h0+h1+h2+h3;
      sQ[q] = h0*h0+h1*h1+h2*h2+h3*h3;
    }
  }
  #pragma unroll
  for (int q = 0; q < 16; q++) {
    mx[q] = fmaxf(mx[q], __shfl_xor(mx[q], 16, 64));
    mn[q] = fminf(mn[q], __shfl_xor(mn[q], 16, 64));
  }
  if ((ty & 1) == 0) {
    int node = (rowbase >> 3) + (ty >> 1);
    #pragma unroll
    for (int q4 = 0; q4 < 4; q4++) {
      *(float4*)&maxK[(size_t)node*DD + q4*64 + tx*4] =
          make_float4(mx[q4*4+0], mx[q4*4+1], mx[q4*4+2], mx[q4*4+3]);
      *(float4*)&minK[(size_t)node*DD + q4*64 + tx*4] =
          make_float4(mn[q4*4+0], mn[q4*4+1], mn[q4*4+2], mn[q4*4+3]);
    }
  }
  #pragma unroll
  for (int q = 0; q < 16; q++) {
    sS[q] += __shfl_xor(sS[q], 16, 64);
    sS[q] += __shfl_xor(sS[q], 32, 64);
    sQ[q] += __shfl_xor(sQ[q], 16, 64);
    sQ[q] += __shfl_xor(sQ[q], 32, 64);
  }
  int w = tid >> 6;
  if ((tid & 63) < 16) {
    #pragma unroll
    for (int q4 = 0; q4 < 4; q4++)
      #pragma unroll
      for (int cc = 0; cc < 4; cc++) {
        redS[w][q4*64 + tx*4 + cc] = sS[q4*4+cc];
        redQ[w][q4*64 + tx*4 + cc] = sQ[q4*4+cc];
      }
  }
  __syncthreads();
  float ts = redS[0][tid]+redS[1][tid]+redS[2][tid]+redS[3][tid];
  float tq = redQ[0][tid]+redQ[1][tid]+redQ[2][tid]+redQ[3][tid];
  int row = blockIdx.x & (NSH - 1);
  atomicAdd(&stats[row*1024 + 512 + tid], ts);
  atomicAdd(&stats[row*1024 + 768 + tid], tq);
}

// ---------------- partial max/min over n (64 rows per block)
__global__ __launch_bounds__(256) void poolpart(const float* __restrict__ maxK, const float* __restrict__ minK,
    float* __restrict__ pmax, float* __restrict__ pmin)
{
  int b = blockIdx.x, ns = blockIdx.y, c = threadIdx.x;
  float mx = -3.4e38f, mn = 3.4e38f;
  size_t base = ((size_t)b*NN + ns*64)*DD + c;
  for (int n = 0; n < 64; n++) {
    mx = fmaxf(mx, maxK[base + (size_t)n*DD]);
    mn = fminf(mn, minK[base + (size_t)n*DD]);
  }
  pmax[((size_t)b*32 + ns)*DD + c] = mx;
  pmin[((size_t)b*32 + ns)*DD + c] = mn;
}

// ---------------- final: BN2 on pooled max/min, two 256x256 linears, l2norm
__global__ __launch_bounds__(256) void finalk(const float* __restrict__ pmax, const float* __restrict__ pmin,
    const float* __restrict__ stats, const float* __restrict__ g2, const float* __restrict__ be2,
    const float* __restrict__ W1, const float* __restrict__ b1,
    const float* __restrict__ W2, const float* __restrict__ b2,
    float* __restrict__ out)
{
  __shared__ float pl[8][256];
  __shared__ float hl[8][256];
  __shared__ float nrm[8];
  int c = threadIdx.x;
  const float inv = 1.f / (float)NEDGE;
  float sm = 0.f, sq2 = 0.f;
  #pragma unroll 1
  for (int r = 0; r < NSH; r++) {
    sm  += stats[r*1024 + 512 + c];
    sq2 += stats[r*1024 + 768 + c];
  }
  float m = sm * inv;
  float var = sq2*inv - m*m;
  float s2 = g2[c] / sqrtf(var + BN_EPS);
  float t2 = be2[c] - m*s2;
  #pragma unroll
  for (int b = 0; b < 8; b++) {
    float mx = -3.4e38f, mn = 3.4e38f;
    for (int ns = 0; ns < 32; ns++) {
      mx = fmaxf(mx, pmax[((size_t)b*32+ns)*DD + c]);
      mn = fminf(mn, pmin[((size_t)b*32+ns)*DD + c]);
    }
    pl[b][c] = (s2 >= 0.f) ? s2*mx + t2 : s2*mn + t2;
  }
  __syncthreads();
  float h[8];
  #pragma unroll
  for (int b = 0; b < 8; b++) h[b] = b1[c];
  for (int k = 0; k < 256; k++) {
    float w = W1[k*256 + c];
    #pragma unroll
    for (int b = 0; b < 8; b++) h[b] += pl[b][k]*w;
  }
  __syncthreads();
  #pragma unroll
  for (int b = 0; b < 8; b++) hl[b][c] = fmaxf(h[b], 0.f);
  __syncthreads();
  float o[8];
  #pragma unroll
  for (int b = 0; b < 8; b++) o[b] = b2[c];
  for (int k = 0; k < 256; k++) {
    float w = W2[k*256 + c];
    #pragma unroll
    for (int b = 0; b < 8; b++) o[b] += hl[b][k]*w;
  }
  __syncthreads();
  #pragma unroll
  for (int b = 0; b < 8; b++) pl[b][c] = fmaxf(o[b], 0.f);
  __syncthreads();
  if (c < 8) {
    float s = 0.f;
    for (int k = 0; k < 256; k++) { float vv = pl[c][k]; s += vv*vv; }
    nrm[c] = fmaxf(sqrtf(s), 1e-12f);
  }
  __syncthreads();
  #pragma unroll
  for (int b = 0; b < 8; b++) out[b*256 + c] = pl[b][c] / nrm[b];
}

extern "C" void kernel_launch(void* const* d_in, const int* in_sizes, int n_in,
                              void* d_out, int out_size, void* d_ws, size_t ws_size,
                              hipStream_t stream) {
  (void)in_sizes; (void)n_in; (void)out_size; (void)ws_size;
  const int*   cls       = (const int*)  d_in[0];
  const float* colors    = (const float*)d_in[1];
  const float* positions = (const float*)d_in[2];
  const float* ctab      = (const float*)d_in[3];
  const float* pW1 = (const float*)d_in[4];
  const float* pb1 = (const float*)d_in[5];
  const float* pW2 = (const float*)d_in[6];
  const float* pb2 = (const float*)d_in[7];
  const float* cW1 = (const float*)d_in[8];
  const float* cb1 = (const float*)d_in[9];
  const float* cW2 = (const float*)d_in[10];
  const float* cb2 = (const float*)d_in[11];
  const float* mW  = (const float*)d_in[12];
  const float* mb  = (const float*)d_in[13];
  const float* gW1 = (const float*)d_in[14];
  const float* gb1 = (const float*)d_in[15];
  const float* gg1 = (const float*)d_in[16];
  const float* gbe1= (const float*)d_in[17];
  const float* gW2 = (const float*)d_in[18];
  const float* gb2 = (const float*)d_in[19];
  const float* gg2 = (const float*)d_in[20];
  const float* gbe2= (const float*)d_in[21];
  const float* lW1 = (const float*)d_in[22];
  const float* lb1 = (const float*)d_in[23];
  const float* lW2 = (const float*)d_in[24];
  const float* lb2 = (const float*)d_in[25];
  float* out = (float*)d_out;

  float* wsf   = (float*)d_ws;
  float* x     = wsf + OFF_X;
  float* feat  = wsf + OFF_FEAT;
  float* sq    = wsf + OFF_SQ;
  int*   idxg  = (int*)(wsf + OFF_IDX);
  float* u     = wsf + OFF_U;
  float* v     = wsf + OFF_V;
  float* Wu    = wsf + OFF_WU;
  float* W2p   = wsf + OFF_W2P;
  float* biasp = wsf + OFF_BIASP;
  float* stats = wsf + OFF_STATS;
  float* maxK  = wsf + OFF_MAXK;
  float* minK  = wsf + OFF_MINK;
  float* pmax  = wsf + OFF_PMAX;
  float* pmin  = wsf + OFF_PMIN;
  // partial kNN buffers overlay feat (dead after the merge GEMM): 32 entries/point
  float* pdg   = feat;
  int*   pjg   = (int*)(feat + (size_t)NPTS*32);

  hipMemsetAsync(stats, 0, NSH*1024*sizeof(float), stream);

  featurize<<<NPTS, 256, 0, stream>>>(cls, colors, positions, ctab,
                                      pW1, pb1, pW2, pb2, cW1, cb1, cW2, cb2, feat);
  gemm64<768, true, true><<<dim3(NPTS/64, 4), 256, 0, stream>>>(feat, mW, mb, x);
  sqk<<<NPTS/4, 256, 0, stream>>>(x, sq);
  prep_wu<<<DD*DD/256, 256, 0, stream>>>(gW1, Wu);
  knnk<<<BB*32*4, 256, 0, stream>>>(x, sq, pdg, pjg);
  knnmerge<<<NPTS/256, 256, 0, stream>>>(pdg, pjg, idxg);
  gemmuv<<<dim3(NPTS/64, 4), 256, 0, stream>>>(x, Wu, gW1 + DD*DD, u, v);
  bn1stats<<<NPTS/32, 256, 0, stream>>>(u, v, idxg, gb1, stats);
  prep2<<<1, 256, 0, stream>>>(stats, gg1, gbe1, gW2, gb2, W2p, biasp);
  edgek<<<NEDGE/64, 256, 0, stream>>>(u, v, idxg, gb1, W2p, biasp, maxK, minK, stats);
  poolpart<<<dim3(BB, 32), 256, 0, stream>>>(maxK, minK, pmax, pmin);
  finalk<<<1, 256, 0, stream>>>(pmax, pmin, stats, gg2, gbe2, lW1, lb1, lW2, lb2, out);
}